// Round 9
// baseline (126.074 us; speedup 1.0000x reference)
//
#include <hip/hip_runtime.h>
#include <hip/hip_bf16.h>
#include <math.h>

#define DMODEL 512
#define T_SEQ 2048
#define NH 8
#define DH 64
#define M_ROWS 4096
#define LDST 72   // padded LDS row stride (retention staging); 144 B = 16B-aligned
#define EPST 136  // epilogue repack stride (272 B = 16B-aligned, 2-way banks)

typedef short s16x8 __attribute__((ext_vector_type(8)));
typedef float f32x4 __attribute__((ext_vector_type(4)));

static __device__ __forceinline__ unsigned short f2bf(float f) {
  __hip_bfloat16 h = __float2bfloat16(f);
  return *(unsigned short*)&h;
}
static __device__ __forceinline__ float bf2f(unsigned short u) {
  union { unsigned int i; float f; } x; x.i = (unsigned int)u << 16; return x.f;
}
// async global->LDS 16B copy; LDS dest must be wave-uniform base + lane*16
static __device__ __forceinline__ void gld16(void* lds, const void* g) {
  __builtin_amdgcn_global_load_lds(
      (const __attribute__((address_space(1))) unsigned int*)g,
      (__attribute__((address_space(3))) unsigned int*)lds, 16, 0, 0);
}

// ---------------------------------------------------------------------------
// Fused prep: blocks 0..1023 cast x -> bf16; blocks 1024..1343 transpose+cast
// the 5 weight matrices into the stacked-row layout:
//   rows    0..511  : W_Q cols | rows 512..1535: [K_h|V_h] x 8 heads
//   rows 1536..2047 : W_G cols | rows 2048..2559: W_O cols
// ---------------------------------------------------------------------------
__global__ __launch_bounds__(256) void prep_k(
    const float* __restrict__ x, unsigned short* __restrict__ Xb,
    const float* __restrict__ W0, const float* __restrict__ W1,
    const float* __restrict__ W2, const float* __restrict__ W3,
    const float* __restrict__ W4, unsigned short* __restrict__ WT)
{
  __shared__ __align__(16) unsigned short buf[64 * LDST];
  const int bid = blockIdx.x, tid = threadIdx.x;
  if (bid < 1024) {
    const size_t i = ((size_t)bid * 256 + tid) * 8;
    float4 a = *(const float4*)&x[i];
    float4 b = *(const float4*)&x[i + 4];
    s16x8 o;
    o[0]=f2bf(a.x); o[1]=f2bf(a.y); o[2]=f2bf(a.z); o[3]=f2bf(a.w);
    o[4]=f2bf(b.x); o[5]=f2bf(b.y); o[6]=f2bf(b.z); o[7]=f2bf(b.w);
    *(s16x8*)&Xb[i] = o;
    return;
  }
  const int bid2 = bid - 1024;
  const int z = bid2 >> 6, rem = bid2 & 63;
  const int n0 = (rem & 7) * 64, k0 = (rem >> 3) * 64;
  const float* W = (z==0)?W0:(z==1)?W1:(z==2)?W2:(z==3)?W3:W4;
  int rowbase;
  if (z == 0)      rowbase = n0;
  else if (z == 1) rowbase = 512 + (n0 >> 6) * 128;        // K_h block
  else if (z == 2) rowbase = 512 + (n0 >> 6) * 128 + 64;   // V_h block
  else if (z == 3) rowbase = 1536 + n0;
  else             rowbase = 2048 + n0;
  #pragma unroll
  for (int r = 0; r < 4; ++r) {
    int idx = r * 256 + tid;
    int kr = idx >> 4, nc = idx & 15;
    float4 v = *(const float4*)&W[(size_t)(k0 + kr) * DMODEL + n0 + nc * 4];
    buf[(nc*4+0) * LDST + kr] = f2bf(v.x);
    buf[(nc*4+1) * LDST + kr] = f2bf(v.y);
    buf[(nc*4+2) * LDST + kr] = f2bf(v.z);
    buf[(nc*4+3) * LDST + kr] = f2bf(v.w);
  }
  __syncthreads();
  #pragma unroll
  for (int r = 0; r < 2; ++r) {
    int idx = r * 256 + tid;
    int nr = idx >> 3, c = idx & 7;
    *(s16x8*)&WT[((size_t)(rowbase + nr)) * DMODEL + k0 + c * 8] =
        *(const s16x8*)&buf[nr * LDST + c * 8];
  }
}

// ---------------------------------------------------------------------------
// Projection GEMM + fused KV outer product; b128 epilogue via LDS repack.
// ---------------------------------------------------------------------------
__global__ __launch_bounds__(256) void proj_kv_k(
    const unsigned short* __restrict__ A, const unsigned short* __restrict__ BT,
    unsigned short* __restrict__ Qb, unsigned short* __restrict__ Kb,
    unsigned short* __restrict__ Vb, unsigned short* __restrict__ Gb,
    float* __restrict__ AT)
{
  __shared__ __align__(16) unsigned short smem[128 * EPST]; // >= 2*128*64
  unsigned short* As = smem;
  unsigned short* Bs = smem + 128 * 64;
  const int ng0 = blockIdx.x * 128;
  const int m0 = blockIdx.y * 128;
  const int tid = threadIdx.x;
  const int wave = tid >> 6, lane = tid & 63;
  const int wm = wave >> 1, wn = wave & 1;
  const int n = lane & 15, quad = lane >> 4;

  int srow[4], scol[4];
  #pragma unroll
  for (int r = 0; r < 4; ++r) {
    int idx = r * 256 + tid;
    srow[r] = idx >> 3;
    scol[r] = ((idx & 7) ^ (srow[r] & 7)) * 8;
  }

  f32x4 acc[4][4];
  #pragma unroll
  for (int mi = 0; mi < 4; ++mi)
    #pragma unroll
    for (int ni = 0; ni < 4; ++ni) acc[mi][ni] = (f32x4){0.f,0.f,0.f,0.f};

  for (int k0 = 0; k0 < 512; k0 += 64) {
    #pragma unroll
    for (int r = 0; r < 4; ++r) {
      int idx = r * 256 + tid;
      gld16(&As[idx * 8], &A[(size_t)(m0 + srow[r]) * DMODEL + k0 + scol[r]]);
      gld16(&Bs[idx * 8], &BT[(size_t)(ng0 + srow[r]) * DMODEL + k0 + scol[r]]);
    }
    __syncthreads();
    #pragma unroll
    for (int kk = 0; kk < 2; ++kk) {
      s16x8 af[4], bf[4];
      #pragma unroll
      for (int mi = 0; mi < 4; ++mi) {
        int R = wm*64 + mi*16 + n, cc = (kk*4 + quad) ^ (n & 7);
        af[mi] = *(const s16x8*)&As[R * 64 + cc * 8];
      }
      #pragma unroll
      for (int ni = 0; ni < 4; ++ni) {
        int R = wn*64 + ni*16 + n, cc = (kk*4 + quad) ^ (n & 7);
        bf[ni] = *(const s16x8*)&Bs[R * 64 + cc * 8];
      }
      #pragma unroll
      for (int mi = 0; mi < 4; ++mi)
        #pragma unroll
        for (int ni = 0; ni < 4; ++ni)
          acc[mi][ni] = __builtin_amdgcn_mfma_f32_16x16x32_bf16(
              af[mi], bf[ni], acc[mi][ni], 0, 0, 0);
    }
    __syncthreads();
  }

  // ---- epilogue: repack acc via LDS (128 x EPST) -> b128 global stores ----
  unsigned short* Ep = smem;
  #pragma unroll
  for (int mi = 0; mi < 4; ++mi)
    #pragma unroll
    for (int ni = 0; ni < 4; ++ni)
      #pragma unroll
      for (int r = 0; r < 4; ++r)
        Ep[(wm*64 + mi*16 + quad*4 + r) * EPST + wn*64 + ni*16 + n] =
            f2bf(acc[mi][ni][r]);
  __syncthreads();

  const int bx = blockIdx.x;
  if (bx < 4 || bx >= 12) {
    unsigned short* Cz = (bx < 4) ? Qb : Gb;
    const int n0 = (bx < 4) ? ng0 : (ng0 - 1536);
    #pragma unroll
    for (int t = 0; t < 8; ++t) {
      int idx = t * 256 + tid;
      int row = idx >> 4, u = idx & 15;
      *(s16x8*)&Cz[(size_t)(m0 + row) * DMODEL + n0 + u * 8] =
          *(const s16x8*)&Ep[row * EPST + u * 8];
    }
    return;
  }

  // KV tile: cols 0..63 = K_h, 64..127 = V_h
  const int h = (ng0 - 512) >> 7;
  const float lg = log2f(1.0f - exp2f(-5.0f - (float)h));
  #pragma unroll
  for (int t = 0; t < 4; ++t) {
    int idx = t * 256 + tid;
    int row = idx >> 3, u = idx & 7;
    *(s16x8*)&Kb[(size_t)(m0 + row) * DMODEL + h*DH + u * 8] =
        *(const s16x8*)&Ep[row * EPST + u * 8];
    *(s16x8*)&Vb[(size_t)(m0 + row) * DMODEL + h*DH + u * 8] =
        *(const s16x8*)&Ep[row * EPST + 64 + u * 8];
  }

  // fused AT: per 64-row chunk, stage scaled K^T and V^T, 8 MFMAs, store
  unsigned short* Kt = smem;                 // [d1][m], LDST stride
  unsigned short* Vt = smem + 64 * LDST;
  #pragma unroll
  for (int cc2 = 0; cc2 < 2; ++cc2) {
    __syncthreads();   // orders Ep reads / prev chunk's MFMA before restage
    if (wm == cc2) {
      unsigned short* Tt = (wn == 0) ? Kt : Vt;
      #pragma unroll
      for (int mi = 0; mi < 4; ++mi)
        #pragma unroll
        for (int r = 0; r < 4; ++r) {
          int m = mi*16 + quad*4 + r;
          float sc = (wn == 0) ? exp2f((float)(64 - m) * lg) : 1.0f;
          #pragma unroll
          for (int ni = 0; ni < 4; ++ni)
            Tt[(ni*16 + n) * LDST + m] = f2bf(acc[mi][ni][r] * sc);
        }
    }
    __syncthreads();
    f32x4 at[4];
    #pragma unroll
    for (int j = 0; j < 4; ++j) at[j] = (f32x4){0.f,0.f,0.f,0.f};
    #pragma unroll
    for (int kk = 0; kk < 2; ++kk) {
      s16x8 a = *(const s16x8*)&Vt[(wave*16 + n) * LDST + kk*32 + quad*8];
      #pragma unroll
      for (int j = 0; j < 4; ++j) {
        s16x8 bf = *(const s16x8*)&Kt[(j*16 + n) * LDST + kk*32 + quad*8];
        at[j] = __builtin_amdgcn_mfma_f32_16x16x32_bf16(a, bf, at[j], 0, 0, 0);
      }
    }
    const int gr = m0 + cc2 * 64;
    const int bb = gr >> 11, cchunk = (gr & 2047) >> 6;
    float* Ab = AT + (((size_t)(bb * NH + h) * 32 + cchunk) << 12);
    #pragma unroll
    for (int j = 0; j < 4; ++j)
      #pragma unroll
      for (int r = 0; r < 4; ++r)
        Ab[(wave*16 + quad*4 + r) * 64 + j*16 + n] = at[j][r];
  }
}

// ---------------------------------------------------------------------------
// Fused scan + retention output + GroupNorm + gate + SiLU.
// Q/K/G staged via gld16 (XOR swizzle); Sb written b128 via Ps repack.
// ---------------------------------------------------------------------------
__global__ __launch_bounds__(256) void ret_o2_k(
    const unsigned short* __restrict__ Qb, const unsigned short* __restrict__ Kb,
    const unsigned short* __restrict__ Vb, const float* __restrict__ AT,
    const unsigned short* __restrict__ Gg, const float* __restrict__ gnw,
    const float* __restrict__ gnb, unsigned short* __restrict__ Sb)
{
  __shared__ __align__(16) unsigned short Qs[64 * 64];    // swizzled
  __shared__ __align__(16) unsigned short Ks[64 * 64];    // swizzled
  __shared__ __align__(16) unsigned short Vst[64 * LDST]; // [d2][m]
  __shared__ __align__(16) unsigned short Ss[64 * LDST];  // [d2][d1]
  __shared__ __align__(16) unsigned short Ps[64 * LDST];
  const int c = (int)gridDim.x - 1 - (int)blockIdx.x;     // heavy chunks first
  const int h = blockIdx.y, b = blockIdx.z;
  const int bh = b * NH + h;
  const int tid = threadIdx.x;
  const int wave = tid >> 6, lane = tid & 63;
  const int n = lane & 15, quad = lane >> 4;
  const size_t base = ((size_t)b * T_SEQ + (size_t)c * 64) * DMODEL + h * DH;
  const float lg = log2f(1.0f - exp2f(-5.0f - (float)h));
  const float g64 = exp2f(64.0f * lg);

  // stage Q, K (async, swizzled) and V^T (VGPR transpose path)
  #pragma unroll
  for (int r = 0; r < 2; ++r) {
    int idx = r * 256 + tid;
    int row = idx >> 3, sc = ((idx & 7) ^ (row & 7)) * 8;
    gld16(&Qs[idx * 8], &Qb[base + (size_t)row * DMODEL + sc]);
    gld16(&Ks[idx * 8], &Kb[base + (size_t)row * DMODEL + sc]);
  }
  #pragma unroll
  for (int r = 0; r < 2; ++r) {
    int idx = r * 256 + tid;
    int m = idx & 63, ch = idx >> 6;
    s16x8 vv = *(const s16x8*)&Vb[base + (size_t)m * DMODEL + ch * 8];
    #pragma unroll
    for (int e = 0; e < 8; ++e)
      Vst[(ch * 8 + e) * LDST + m] = ((unsigned short*)&vv)[e];
  }

  // Horner prefix: S_c = sum_{cp<c} g64^(c-1-cp) * A[cp], 16 elems/thread
  const float* Ac = AT + (((size_t)bh * 32) << 12) + (size_t)tid * 16;
  float4 S0 = {0,0,0,0}, S1 = S0, S2 = S0, S3 = S0;
  if (c > 0) {
    float4 n0 = *(const float4*)(Ac + 0);
    float4 n1 = *(const float4*)(Ac + 4);
    float4 n2 = *(const float4*)(Ac + 8);
    float4 n3 = *(const float4*)(Ac + 12);
    for (int cp = 0; cp < c; ++cp) {
      float4 a0 = n0, a1 = n1, a2 = n2, a3 = n3;
      if (cp + 1 < c) {
        const float* p = Ac + ((size_t)(cp + 1) << 12);
        n0 = *(const float4*)(p + 0);  n1 = *(const float4*)(p + 4);
        n2 = *(const float4*)(p + 8);  n3 = *(const float4*)(p + 12);
      }
      S0.x = fmaf(g64, S0.x, a0.x); S0.y = fmaf(g64, S0.y, a0.y);
      S0.z = fmaf(g64, S0.z, a0.z); S0.w = fmaf(g64, S0.w, a0.w);
      S1.x = fmaf(g64, S1.x, a1.x); S1.y = fmaf(g64, S1.y, a1.y);
      S1.z = fmaf(g64, S1.z, a1.z); S1.w = fmaf(g64, S1.w, a1.w);
      S2.x = fmaf(g64, S2.x, a2.x); S2.y = fmaf(g64, S2.y, a2.y);
      S2.z = fmaf(g64, S2.z, a2.z); S2.w = fmaf(g64, S2.w, a2.w);
      S3.x = fmaf(g64, S3.x, a3.x); S3.y = fmaf(g64, S3.y, a3.y);
      S3.z = fmaf(g64, S3.z, a3.z); S3.w = fmaf(g64, S3.w, a3.w);
    }
  }
  {
    const int d2 = tid >> 2, d1b = (tid & 3) * 16;
    s16x8 lo, hi;
    lo[0]=f2bf(S0.x); lo[1]=f2bf(S0.y); lo[2]=f2bf(S0.z); lo[3]=f2bf(S0.w);
    lo[4]=f2bf(S1.x); lo[5]=f2bf(S1.y); lo[6]=f2bf(S1.z); lo[7]=f2bf(S1.w);
    hi[0]=f2bf(S2.x); hi[1]=f2bf(S2.y); hi[2]=f2bf(S2.z); hi[3]=f2bf(S2.w);
    hi[4]=f2bf(S3.x); hi[5]=f2bf(S3.y); hi[6]=f2bf(S3.z); hi[7]=f2bf(S3.w);
    *(s16x8*)&Ss[d2 * LDST + d1b] = lo;
    *(s16x8*)&Ss[d2 * LDST + d1b + 8] = hi;
  }
  __syncthreads();  // drains Q/K gld16 + Vst/Ss writes

  f32x4 s[4], u[4];
  #pragma unroll
  for (int j = 0; j < 4; ++j) {
    s[j] = (f32x4){0.f,0.f,0.f,0.f};
    u[j] = (f32x4){0.f,0.f,0.f,0.f};
  }
  const int RA = wave*16 + n;
  #pragma unroll
  for (int kk = 0; kk < 2; ++kk) {
    s16x8 a = *(const s16x8*)&Qs[RA * 64 + (((kk*4 + quad) ^ (RA & 7)) * 8)];
    #pragma unroll
    for (int j = 0; j < 4; ++j) {
      int RB = j*16 + n;
      s16x8 bk = *(const s16x8*)&Ks[RB * 64 + (((kk*4 + quad) ^ (RB & 7)) * 8)];
      s[j] = __builtin_amdgcn_mfma_f32_16x16x32_bf16(a, bk, s[j], 0, 0, 0);
      s16x8 bs = *(const s16x8*)&Ss[RB * LDST + kk*32 + quad*8];
      u[j] = __builtin_amdgcn_mfma_f32_16x16x32_bf16(a, bs, u[j], 0, 0, 0);
    }
  }

  float rowf[4], colf[4];
  #pragma unroll
  for (int r = 0; r < 4; ++r) rowf[r] = exp2f((float)(wave*16 + quad*4 + r) * lg);
  #pragma unroll
  for (int j = 0; j < 4; ++j) colf[j] = exp2f(-(float)(j*16 + n) * lg);

  #pragma unroll
  for (int j = 0; j < 4; ++j)
    #pragma unroll
    for (int r = 0; r < 4; ++r) {
      int i = wave*16 + quad*4 + r, mcol = j*16 + n;
      float v = (mcol <= i) ? s[j][r] * 0.125f * rowf[r] * colf[j] : 0.0f;
      Ps[i * LDST + mcol] = f2bf(v);
    }
  __syncthreads();  // all QK reads of Qs done; Ps ready

  // prefetch G tile into Qs (now dead) for the epilogue
  #pragma unroll
  for (int r = 0; r < 2; ++r) {
    int idx = r * 256 + tid;
    int row = idx >> 3, sc = ((idx & 7) ^ (row & 7)) * 8;
    gld16(&Qs[idx * 8], &Gg[base + (size_t)row * DMODEL + sc]);
  }

  f32x4 acc[4];
  #pragma unroll
  for (int j = 0; j < 4; ++j) acc[j] = (f32x4){0.f,0.f,0.f,0.f};
  #pragma unroll
  for (int kk = 0; kk < 2; ++kk) {
    s16x8 a = *(const s16x8*)&Ps[RA * LDST + kk*32 + quad*8];
    #pragma unroll
    for (int j = 0; j < 4; ++j) {
      s16x8 bf = *(const s16x8*)&Vst[(j*16 + n) * LDST + kk*32 + quad*8];
      acc[j] = __builtin_amdgcn_mfma_f32_16x16x32_bf16(a, bf, acc[j], 0, 0, 0);
    }
  }

  float ov[4][4];
  #pragma unroll
  for (int j = 0; j < 4; ++j)
    #pragma unroll
    for (int r = 0; r < 4; ++r)
      ov[j][r] = acc[j][r] + 0.125f * rowf[r] * u[j][r];

  float gw[4], gb[4];
  #pragma unroll
  for (int j = 0; j < 4; ++j) {
    gw[j] = gnw[h*DH + j*16 + n];
    gb[j] = gnb[h*DH + j*16 + n];
  }

  // GroupNorm stats (group == head; tile holds the full group) -> normed regs
  float normed[4][4];
  #pragma unroll
  for (int r = 0; r < 4; ++r) {
    float sum = ov[0][r] + ov[1][r] + ov[2][r] + ov[3][r];
    float sq  = ov[0][r]*ov[0][r] + ov[1][r]*ov[1][r]
              + ov[2][r]*ov[2][r] + ov[3][r]*ov[3][r];
    #pragma unroll
    for (int off = 8; off > 0; off >>= 1) {
      sum += __shfl_xor(sum, off, 64);
      sq  += __shfl_xor(sq,  off, 64);
    }
    const float mean = sum * (1.0f / 64.0f);
    float var = sq * (1.0f / 64.0f) - mean * mean;
    var = fmaxf(var, 0.0f);
    const float rstd = rsqrtf(var + 1e-5f);
    #pragma unroll
    for (int j = 0; j < 4; ++j)
      normed[j][r] = (ov[j][r] - mean) * rstd * gw[j] + gb[j];
  }

  __syncthreads();  // all PV reads of Ps done; G gld16 drained

  // gate + SiLU, repack into Ps, then b128 stores
  #pragma unroll
  for (int r = 0; r < 4; ++r) {
    const int i = wave*16 + quad*4 + r;
    #pragma unroll
    for (int j = 0; j < 4; ++j) {
      const int col = j*16 + n;
      const int gidx = i * 64 + (((col >> 3) ^ (i & 7)) * 8) + (col & 7);
      float uu = bf2f(Qs[gidx]) + normed[j][r];
      Ps[i * LDST + col] = f2bf(uu / (1.0f + expf(-uu)));
    }
  }
  __syncthreads();
  #pragma unroll
  for (int t = 0; t < 2; ++t) {
    int idx = t * 256 + tid;
    int row = idx >> 3, u8 = idx & 7;
    *(s16x8*)&Sb[base + (size_t)row * DMODEL + u8 * 8] =
        *(const s16x8*)&Ps[row * LDST + u8 * 8];
  }
}

// ---------------------------------------------------------------------------
// Output GEMM: out = Sb(4096x512 bf16) @ WO^T, fp32. 128x64 tile -> 256 blocks.
// ---------------------------------------------------------------------------
__global__ __launch_bounds__(256) void out_gemm_k(
    const unsigned short* __restrict__ A, const unsigned short* __restrict__ BT,
    float* __restrict__ out)
{
  __shared__ __align__(16) unsigned short As[128 * 64];
  __shared__ __align__(16) unsigned short Bs[64 * 64];
  const int n0 = blockIdx.x * 64;
  const int m0 = blockIdx.y * 128;
  const int tid = threadIdx.x;
  const int wave = tid >> 6, lane = tid & 63;
  const int wm = wave >> 1, wn = wave & 1;
  const int n = lane & 15, quad = lane >> 4;

  int srow[4], scol[4];
  #pragma unroll
  for (int r = 0; r < 4; ++r) {
    int idx = r * 256 + tid;
    srow[r] = idx >> 3;
    scol[r] = ((idx & 7) ^ (srow[r] & 7)) * 8;
  }

  f32x4 acc[4][2];
  #pragma unroll
  for (int mi = 0; mi < 4; ++mi)
    #pragma unroll
    for (int ni = 0; ni < 2; ++ni) acc[mi][ni] = (f32x4){0.f,0.f,0.f,0.f};

  for (int k0 = 0; k0 < 512; k0 += 64) {
    #pragma unroll
    for (int r = 0; r < 4; ++r) {
      int idx = r * 256 + tid;
      gld16(&As[idx * 8], &A[(size_t)(m0 + srow[r]) * DMODEL + k0 + scol[r]]);
    }
    #pragma unroll
    for (int r = 0; r < 2; ++r) {
      int idx = r * 256 + tid;
      gld16(&Bs[idx * 8], &BT[(size_t)(n0 + srow[r]) * DMODEL + k0 + scol[r]]);
    }
    __syncthreads();
    #pragma unroll
    for (int kk = 0; kk < 2; ++kk) {
      s16x8 af[4], bf[2];
      #pragma unroll
      for (int mi = 0; mi < 4; ++mi) {
        int R = wm*64 + mi*16 + n, cc = (kk*4 + quad) ^ (n & 7);
        af[mi] = *(const s16x8*)&As[R * 64 + cc * 8];
      }
      #pragma unroll
      for (int ni = 0; ni < 2; ++ni) {
        int R = wn*32 + ni*16 + n, cc = (kk*4 + quad) ^ (n & 7);
        bf[ni] = *(const s16x8*)&Bs[R * 64 + cc * 8];
      }
      #pragma unroll
      for (int mi = 0; mi < 4; ++mi)
        #pragma unroll
        for (int ni = 0; ni < 2; ++ni)
          acc[mi][ni] = __builtin_amdgcn_mfma_f32_16x16x32_bf16(
              af[mi], bf[ni], acc[mi][ni], 0, 0, 0);
    }
    __syncthreads();
  }

  #pragma unroll
  for (int mi = 0; mi < 4; ++mi)
    #pragma unroll
    for (int ni = 0; ni < 2; ++ni)
      #pragma unroll
      for (int r = 0; r < 4; ++r)
        out[(size_t)(m0 + wm*64 + mi*16 + quad*4 + r) * DMODEL +
            n0 + wn*32 + ni*16 + n] = acc[mi][ni][r];
}

// ---------------------------------------------------------------------------
extern "C" void kernel_launch(void* const* d_in, const int* in_sizes, int n_in,
                              void* d_out, int out_size, void* d_ws, size_t ws_size,
                              hipStream_t stream) {
  const float* x   = (const float*)d_in[0];
  const float* WQ  = (const float*)d_in[1];
  const float* WK  = (const float*)d_in[2];
  const float* WV  = (const float*)d_in[3];
  const float* WG  = (const float*)d_in[4];
  const float* WO  = (const float*)d_in[5];
  const float* gnw = (const float*)d_in[6];
  const float* gnb = (const float*)d_in[7];
  float* out = (float*)d_out;

  char* ws = (char*)d_ws;
  unsigned short* Xb = (unsigned short*)(ws);                 // 4 MB
  unsigned short* Qb = (unsigned short*)(ws + 4  * (1<<20));  // 4 MB
  unsigned short* Kb = (unsigned short*)(ws + 8  * (1<<20));  // 4 MB
  unsigned short* Vb = (unsigned short*)(ws + 12 * (1<<20));  // 4 MB
  unsigned short* G  = (unsigned short*)(ws + 16 * (1<<20));  // 4 MB (bf16)
  float* AT  = (float*)(ws + 24 * (1<<20));                   // 8 MB
  unsigned short* Sb = (unsigned short*)(ws + 32 * (1<<20));  // 4 MB
  unsigned short* WT = (unsigned short*)(ws + 40 * (1<<20));  // 2.5 MB
  (void)ws_size;

  // 1) fused cast-x + weight transpose/stacking
  prep_k<<<dim3(1024 + 320), 256, 0, stream>>>(x, Xb, WQ, WK, WV, WG, WO, WT);
  // 2) projections + fused per-chunk KV outer products
  proj_kv_k<<<dim3(16, M_ROWS / 128), 256, 0, stream>>>(
      Xb, WT, Qb, Kb, Vb, G, AT);
  // 3) fused prefix-scan + retention output + GroupNorm + gate + SiLU
  ret_o2_k<<<dim3(T_SEQ / 64, NH, 2), 256, 0, stream>>>(
      Qb, Kb, Vb, AT, G, gnw, gnb, Sb);
  // 4) output projection (fp32 out), 256 blocks
  out_gemm_k<<<dim3(8, M_ROWS / 128), 256, 0, stream>>>(
      Sb, WT + 2048 * DMODEL, out);
}

// Round 10
// 125.195 us; speedup vs baseline: 1.0070x; 1.0070x over previous
//
#include <hip/hip_runtime.h>
#include <hip/hip_bf16.h>
#include <math.h>

#define DMODEL 512
#define T_SEQ 2048
#define NH 8
#define DH 64
#define M_ROWS 4096
#define LDST 72   // padded LDS row stride (retention staging); 144 B = 16B-aligned
#define EPST 136  // epilogue repack stride (272 B = 16B-aligned, 2-way banks)

typedef short s16x8 __attribute__((ext_vector_type(8)));
typedef float f32x4 __attribute__((ext_vector_type(4)));

static __device__ __forceinline__ unsigned short f2bf(float f) {
  __hip_bfloat16 h = __float2bfloat16(f);
  return *(unsigned short*)&h;
}
static __device__ __forceinline__ float bf2f(unsigned short u) {
  union { unsigned int i; float f; } x; x.i = (unsigned int)u << 16; return x.f;
}
// async global->LDS 16B copy; LDS dest must be wave-uniform base + lane*16
static __device__ __forceinline__ void gld16(void* lds, const void* g) {
  __builtin_amdgcn_global_load_lds(
      (const __attribute__((address_space(1))) unsigned int*)g,
      (__attribute__((address_space(3))) unsigned int*)lds, 16, 0, 0);
}

// ---------------------------------------------------------------------------
// Fused prep: blocks 0..1023 cast x -> bf16; blocks 1024..1343 transpose+cast
// the 5 weight matrices into the stacked-row layout:
//   rows    0..511  : W_Q cols | rows 512..1535: [K_h|V_h] x 8 heads
//   rows 1536..2047 : W_G cols | rows 2048..2559: W_O cols
// ---------------------------------------------------------------------------
__global__ __launch_bounds__(256) void prep_k(
    const float* __restrict__ x, unsigned short* __restrict__ Xb,
    const float* __restrict__ W0, const float* __restrict__ W1,
    const float* __restrict__ W2, const float* __restrict__ W3,
    const float* __restrict__ W4, unsigned short* __restrict__ WT)
{
  __shared__ __align__(16) unsigned short buf[64 * LDST];
  const int bid = blockIdx.x, tid = threadIdx.x;
  if (bid < 1024) {
    const size_t i = ((size_t)bid * 256 + tid) * 8;
    float4 a = *(const float4*)&x[i];
    float4 b = *(const float4*)&x[i + 4];
    s16x8 o;
    o[0]=f2bf(a.x); o[1]=f2bf(a.y); o[2]=f2bf(a.z); o[3]=f2bf(a.w);
    o[4]=f2bf(b.x); o[5]=f2bf(b.y); o[6]=f2bf(b.z); o[7]=f2bf(b.w);
    *(s16x8*)&Xb[i] = o;
    return;
  }
  const int bid2 = bid - 1024;
  const int z = bid2 >> 6, rem = bid2 & 63;
  const int n0 = (rem & 7) * 64, k0 = (rem >> 3) * 64;
  const float* W = (z==0)?W0:(z==1)?W1:(z==2)?W2:(z==3)?W3:W4;
  int rowbase;
  if (z == 0)      rowbase = n0;
  else if (z == 1) rowbase = 512 + (n0 >> 6) * 128;        // K_h block
  else if (z == 2) rowbase = 512 + (n0 >> 6) * 128 + 64;   // V_h block
  else if (z == 3) rowbase = 1536 + n0;
  else             rowbase = 2048 + n0;
  #pragma unroll
  for (int r = 0; r < 4; ++r) {
    int idx = r * 256 + tid;
    int kr = idx >> 4, nc = idx & 15;
    float4 v = *(const float4*)&W[(size_t)(k0 + kr) * DMODEL + n0 + nc * 4];
    buf[(nc*4+0) * LDST + kr] = f2bf(v.x);
    buf[(nc*4+1) * LDST + kr] = f2bf(v.y);
    buf[(nc*4+2) * LDST + kr] = f2bf(v.z);
    buf[(nc*4+3) * LDST + kr] = f2bf(v.w);
  }
  __syncthreads();
  #pragma unroll
  for (int r = 0; r < 2; ++r) {
    int idx = r * 256 + tid;
    int nr = idx >> 3, c = idx & 7;
    *(s16x8*)&WT[((size_t)(rowbase + nr)) * DMODEL + k0 + c * 8] =
        *(const s16x8*)&buf[nr * LDST + c * 8];
  }
}

// ---------------------------------------------------------------------------
// Projection GEMM + fused KV outer product; b128 epilogue via LDS repack.
// ---------------------------------------------------------------------------
__global__ __launch_bounds__(256) void proj_kv_k(
    const unsigned short* __restrict__ A, const unsigned short* __restrict__ BT,
    unsigned short* __restrict__ Qb, unsigned short* __restrict__ Kb,
    unsigned short* __restrict__ Vb, unsigned short* __restrict__ Gb,
    float* __restrict__ AT)
{
  __shared__ __align__(16) unsigned short smem[128 * EPST]; // >= 2*128*64
  unsigned short* As = smem;
  unsigned short* Bs = smem + 128 * 64;
  const int ng0 = blockIdx.x * 128;
  const int m0 = blockIdx.y * 128;
  const int tid = threadIdx.x;
  const int wave = tid >> 6, lane = tid & 63;
  const int wm = wave >> 1, wn = wave & 1;
  const int n = lane & 15, quad = lane >> 4;

  int srow[4], scol[4];
  #pragma unroll
  for (int r = 0; r < 4; ++r) {
    int idx = r * 256 + tid;
    srow[r] = idx >> 3;
    scol[r] = ((idx & 7) ^ (srow[r] & 7)) * 8;
  }

  f32x4 acc[4][4];
  #pragma unroll
  for (int mi = 0; mi < 4; ++mi)
    #pragma unroll
    for (int ni = 0; ni < 4; ++ni) acc[mi][ni] = (f32x4){0.f,0.f,0.f,0.f};

  for (int k0 = 0; k0 < 512; k0 += 64) {
    #pragma unroll
    for (int r = 0; r < 4; ++r) {
      int idx = r * 256 + tid;
      gld16(&As[idx * 8], &A[(size_t)(m0 + srow[r]) * DMODEL + k0 + scol[r]]);
      gld16(&Bs[idx * 8], &BT[(size_t)(ng0 + srow[r]) * DMODEL + k0 + scol[r]]);
    }
    __syncthreads();
    #pragma unroll
    for (int kk = 0; kk < 2; ++kk) {
      s16x8 af[4], bf[4];
      #pragma unroll
      for (int mi = 0; mi < 4; ++mi) {
        int R = wm*64 + mi*16 + n, cc = (kk*4 + quad) ^ (n & 7);
        af[mi] = *(const s16x8*)&As[R * 64 + cc * 8];
      }
      #pragma unroll
      for (int ni = 0; ni < 4; ++ni) {
        int R = wn*64 + ni*16 + n, cc = (kk*4 + quad) ^ (n & 7);
        bf[ni] = *(const s16x8*)&Bs[R * 64 + cc * 8];
      }
      #pragma unroll
      for (int mi = 0; mi < 4; ++mi)
        #pragma unroll
        for (int ni = 0; ni < 4; ++ni)
          acc[mi][ni] = __builtin_amdgcn_mfma_f32_16x16x32_bf16(
              af[mi], bf[ni], acc[mi][ni], 0, 0, 0);
    }
    __syncthreads();
  }

  // ---- epilogue: repack acc via LDS (128 x EPST) -> b128 global stores ----
  unsigned short* Ep = smem;
  #pragma unroll
  for (int mi = 0; mi < 4; ++mi)
    #pragma unroll
    for (int ni = 0; ni < 4; ++ni)
      #pragma unroll
      for (int r = 0; r < 4; ++r)
        Ep[(wm*64 + mi*16 + quad*4 + r) * EPST + wn*64 + ni*16 + n] =
            f2bf(acc[mi][ni][r]);
  __syncthreads();

  const int bx = blockIdx.x;
  if (bx < 4 || bx >= 12) {
    unsigned short* Cz = (bx < 4) ? Qb : Gb;
    const int n0 = (bx < 4) ? ng0 : (ng0 - 1536);
    #pragma unroll
    for (int t = 0; t < 8; ++t) {
      int idx = t * 256 + tid;
      int row = idx >> 4, u = idx & 15;
      *(s16x8*)&Cz[(size_t)(m0 + row) * DMODEL + n0 + u * 8] =
          *(const s16x8*)&Ep[row * EPST + u * 8];
    }
    return;
  }

  // KV tile: cols 0..63 = K_h, 64..127 = V_h
  const int h = (ng0 - 512) >> 7;
  const float lg = log2f(1.0f - exp2f(-5.0f - (float)h));
  #pragma unroll
  for (int t = 0; t < 4; ++t) {
    int idx = t * 256 + tid;
    int row = idx >> 3, u = idx & 7;
    *(s16x8*)&Kb[(size_t)(m0 + row) * DMODEL + h*DH + u * 8] =
        *(const s16x8*)&Ep[row * EPST + u * 8];
    *(s16x8*)&Vb[(size_t)(m0 + row) * DMODEL + h*DH + u * 8] =
        *(const s16x8*)&Ep[row * EPST + 64 + u * 8];
  }

  // fused AT: per 64-row chunk, stage scaled K^T and V^T, 8 MFMAs, store
  unsigned short* Kt = smem;                 // [d1][m], LDST stride
  unsigned short* Vt = smem + 64 * LDST;
  #pragma unroll
  for (int cc2 = 0; cc2 < 2; ++cc2) {
    __syncthreads();   // orders Ep reads / prev chunk's MFMA before restage
    if (wm == cc2) {
      unsigned short* Tt = (wn == 0) ? Kt : Vt;
      #pragma unroll
      for (int mi = 0; mi < 4; ++mi)
        #pragma unroll
        for (int r = 0; r < 4; ++r) {
          int m = mi*16 + quad*4 + r;
          float sc = (wn == 0) ? exp2f((float)(64 - m) * lg) : 1.0f;
          #pragma unroll
          for (int ni = 0; ni < 4; ++ni)
            Tt[(ni*16 + n) * LDST + m] = f2bf(acc[mi][ni][r] * sc);
        }
    }
    __syncthreads();
    f32x4 at[4];
    #pragma unroll
    for (int j = 0; j < 4; ++j) at[j] = (f32x4){0.f,0.f,0.f,0.f};
    #pragma unroll
    for (int kk = 0; kk < 2; ++kk) {
      s16x8 a = *(const s16x8*)&Vt[(wave*16 + n) * LDST + kk*32 + quad*8];
      #pragma unroll
      for (int j = 0; j < 4; ++j) {
        s16x8 bf = *(const s16x8*)&Kt[(j*16 + n) * LDST + kk*32 + quad*8];
        at[j] = __builtin_amdgcn_mfma_f32_16x16x32_bf16(a, bf, at[j], 0, 0, 0);
      }
    }
    const int gr = m0 + cc2 * 64;
    const int bb = gr >> 11, cchunk = (gr & 2047) >> 6;
    float* Ab = AT + (((size_t)(bb * NH + h) * 32 + cchunk) << 12);
    #pragma unroll
    for (int j = 0; j < 4; ++j)
      #pragma unroll
      for (int r = 0; r < 4; ++r)
        Ab[(wave*16 + quad*4 + r) * 64 + j*16 + n] = at[j][r];
  }
}

// ---------------------------------------------------------------------------
// Fused scan + retention output + GroupNorm + gate + SiLU.
// Scan is a PARALLEL weighted sum (w_cp = g64^(c-1-cp)), unroll-4 pipelined --
// no loop-carried dependence through the loaded AT data.
// ---------------------------------------------------------------------------
__global__ __launch_bounds__(256) void ret_o2_k(
    const unsigned short* __restrict__ Qb, const unsigned short* __restrict__ Kb,
    const unsigned short* __restrict__ Vb, const float* __restrict__ AT,
    const unsigned short* __restrict__ Gg, const float* __restrict__ gnw,
    const float* __restrict__ gnb, unsigned short* __restrict__ Sb)
{
  __shared__ __align__(16) unsigned short Qs[64 * 64];    // swizzled
  __shared__ __align__(16) unsigned short Ks[64 * 64];    // swizzled
  __shared__ __align__(16) unsigned short Vst[64 * LDST]; // [d2][m]
  __shared__ __align__(16) unsigned short Ss[64 * LDST];  // [d2][d1]
  __shared__ __align__(16) unsigned short Ps[64 * LDST];
  const int c = (int)gridDim.x - 1 - (int)blockIdx.x;     // heavy chunks first
  const int h = blockIdx.y, b = blockIdx.z;
  const int bh = b * NH + h;
  const int tid = threadIdx.x;
  const int wave = tid >> 6, lane = tid & 63;
  const int n = lane & 15, quad = lane >> 4;
  const size_t base = ((size_t)b * T_SEQ + (size_t)c * 64) * DMODEL + h * DH;
  const float lg = log2f(1.0f - exp2f(-5.0f - (float)h));
  const float lg64 = 64.0f * lg;

  // stage Q, K (async, swizzled) and V^T (VGPR transpose path)
  #pragma unroll
  for (int r = 0; r < 2; ++r) {
    int idx = r * 256 + tid;
    int row = idx >> 3, sc = ((idx & 7) ^ (row & 7)) * 8;
    gld16(&Qs[idx * 8], &Qb[base + (size_t)row * DMODEL + sc]);
    gld16(&Ks[idx * 8], &Kb[base + (size_t)row * DMODEL + sc]);
  }
  #pragma unroll
  for (int r = 0; r < 2; ++r) {
    int idx = r * 256 + tid;
    int m = idx & 63, ch = idx >> 6;
    s16x8 vv = *(const s16x8*)&Vb[base + (size_t)m * DMODEL + ch * 8];
    #pragma unroll
    for (int e = 0; e < 8; ++e)
      Vst[(ch * 8 + e) * LDST + m] = ((unsigned short*)&vv)[e];
  }

  // parallel weighted-sum scan: S_c = sum_{cp<c} g64^(c-1-cp) * A[cp]
  // (ascending cp: smallest weights first; loads independent across iters)
  const float* Ac = AT + (((size_t)bh * 32) << 12) + (size_t)tid * 16;
  float4 S0 = {0,0,0,0}, S1 = S0, S2 = S0, S3 = S0;
  #pragma unroll 4
  for (int cp = 0; cp < c; ++cp) {
    const float* p = Ac + ((size_t)cp << 12);
    const float w = exp2f((float)(c - 1 - cp) * lg64);
    float4 a0 = *(const float4*)(p + 0);
    float4 a1 = *(const float4*)(p + 4);
    float4 a2 = *(const float4*)(p + 8);
    float4 a3 = *(const float4*)(p + 12);
    S0.x = fmaf(w, a0.x, S0.x); S0.y = fmaf(w, a0.y, S0.y);
    S0.z = fmaf(w, a0.z, S0.z); S0.w = fmaf(w, a0.w, S0.w);
    S1.x = fmaf(w, a1.x, S1.x); S1.y = fmaf(w, a1.y, S1.y);
    S1.z = fmaf(w, a1.z, S1.z); S1.w = fmaf(w, a1.w, S1.w);
    S2.x = fmaf(w, a2.x, S2.x); S2.y = fmaf(w, a2.y, S2.y);
    S2.z = fmaf(w, a2.z, S2.z); S2.w = fmaf(w, a2.w, S2.w);
    S3.x = fmaf(w, a3.x, S3.x); S3.y = fmaf(w, a3.y, S3.y);
    S3.z = fmaf(w, a3.z, S3.z); S3.w = fmaf(w, a3.w, S3.w);
  }
  {
    const int d2 = tid >> 2, d1b = (tid & 3) * 16;
    s16x8 lo, hi;
    lo[0]=f2bf(S0.x); lo[1]=f2bf(S0.y); lo[2]=f2bf(S0.z); lo[3]=f2bf(S0.w);
    lo[4]=f2bf(S1.x); lo[5]=f2bf(S1.y); lo[6]=f2bf(S1.z); lo[7]=f2bf(S1.w);
    hi[0]=f2bf(S2.x); hi[1]=f2bf(S2.y); hi[2]=f2bf(S2.z); hi[3]=f2bf(S2.w);
    hi[4]=f2bf(S3.x); hi[5]=f2bf(S3.y); hi[6]=f2bf(S3.z); hi[7]=f2bf(S3.w);
    *(s16x8*)&Ss[d2 * LDST + d1b] = lo;
    *(s16x8*)&Ss[d2 * LDST + d1b + 8] = hi;
  }
  __syncthreads();  // drains Q/K gld16 + Vst/Ss writes

  f32x4 s[4], u[4];
  #pragma unroll
  for (int j = 0; j < 4; ++j) {
    s[j] = (f32x4){0.f,0.f,0.f,0.f};
    u[j] = (f32x4){0.f,0.f,0.f,0.f};
  }
  const int RA = wave*16 + n;
  #pragma unroll
  for (int kk = 0; kk < 2; ++kk) {
    s16x8 a = *(const s16x8*)&Qs[RA * 64 + (((kk*4 + quad) ^ (RA & 7)) * 8)];
    #pragma unroll
    for (int j = 0; j < 4; ++j) {
      int RB = j*16 + n;
      s16x8 bk = *(const s16x8*)&Ks[RB * 64 + (((kk*4 + quad) ^ (RB & 7)) * 8)];
      s[j] = __builtin_amdgcn_mfma_f32_16x16x32_bf16(a, bk, s[j], 0, 0, 0);
      s16x8 bs = *(const s16x8*)&Ss[RB * LDST + kk*32 + quad*8];
      u[j] = __builtin_amdgcn_mfma_f32_16x16x32_bf16(a, bs, u[j], 0, 0, 0);
    }
  }

  float rowf[4], colf[4];
  #pragma unroll
  for (int r = 0; r < 4; ++r) rowf[r] = exp2f((float)(wave*16 + quad*4 + r) * lg);
  #pragma unroll
  for (int j = 0; j < 4; ++j) colf[j] = exp2f(-(float)(j*16 + n) * lg);

  #pragma unroll
  for (int j = 0; j < 4; ++j)
    #pragma unroll
    for (int r = 0; r < 4; ++r) {
      int i = wave*16 + quad*4 + r, mcol = j*16 + n;
      float v = (mcol <= i) ? s[j][r] * 0.125f * rowf[r] * colf[j] : 0.0f;
      Ps[i * LDST + mcol] = f2bf(v);
    }
  __syncthreads();  // all QK reads of Qs done; Ps ready

  // prefetch G tile into Qs (now dead) for the epilogue
  #pragma unroll
  for (int r = 0; r < 2; ++r) {
    int idx = r * 256 + tid;
    int row = idx >> 3, sc = ((idx & 7) ^ (row & 7)) * 8;
    gld16(&Qs[idx * 8], &Gg[base + (size_t)row * DMODEL + sc]);
  }

  f32x4 acc[4];
  #pragma unroll
  for (int j = 0; j < 4; ++j) acc[j] = (f32x4){0.f,0.f,0.f,0.f};
  #pragma unroll
  for (int kk = 0; kk < 2; ++kk) {
    s16x8 a = *(const s16x8*)&Ps[RA * LDST + kk*32 + quad*8];
    #pragma unroll
    for (int j = 0; j < 4; ++j) {
      s16x8 bf = *(const s16x8*)&Vst[(j*16 + n) * LDST + kk*32 + quad*8];
      acc[j] = __builtin_amdgcn_mfma_f32_16x16x32_bf16(a, bf, acc[j], 0, 0, 0);
    }
  }

  float ov[4][4];
  #pragma unroll
  for (int j = 0; j < 4; ++j)
    #pragma unroll
    for (int r = 0; r < 4; ++r)
      ov[j][r] = acc[j][r] + 0.125f * rowf[r] * u[j][r];

  float gw[4], gb[4];
  #pragma unroll
  for (int j = 0; j < 4; ++j) {
    gw[j] = gnw[h*DH + j*16 + n];
    gb[j] = gnb[h*DH + j*16 + n];
  }

  // GroupNorm stats (group == head; tile holds the full group) -> normed regs
  float normed[4][4];
  #pragma unroll
  for (int r = 0; r < 4; ++r) {
    float sum = ov[0][r] + ov[1][r] + ov[2][r] + ov[3][r];
    float sq  = ov[0][r]*ov[0][r] + ov[1][r]*ov[1][r]
              + ov[2][r]*ov[2][r] + ov[3][r]*ov[3][r];
    #pragma unroll
    for (int off = 8; off > 0; off >>= 1) {
      sum += __shfl_xor(sum, off, 64);
      sq  += __shfl_xor(sq,  off, 64);
    }
    const float mean = sum * (1.0f / 64.0f);
    float var = sq * (1.0f / 64.0f) - mean * mean;
    var = fmaxf(var, 0.0f);
    const float rstd = rsqrtf(var + 1e-5f);
    #pragma unroll
    for (int j = 0; j < 4; ++j)
      normed[j][r] = (ov[j][r] - mean) * rstd * gw[j] + gb[j];
  }

  __syncthreads();  // all PV reads of Ps done; G gld16 drained

  // gate + SiLU, repack into Ps, then b128 stores
  #pragma unroll
  for (int r = 0; r < 4; ++r) {
    const int i = wave*16 + quad*4 + r;
    #pragma unroll
    for (int j = 0; j < 4; ++j) {
      const int col = j*16 + n;
      const int gidx = i * 64 + (((col >> 3) ^ (i & 7)) * 8) + (col & 7);
      float uu = bf2f(Qs[gidx]) + normed[j][r];
      Ps[i * LDST + col] = f2bf(uu / (1.0f + expf(-uu)));
    }
  }
  __syncthreads();
  #pragma unroll
  for (int t = 0; t < 2; ++t) {
    int idx = t * 256 + tid;
    int row = idx >> 3, u8 = idx & 7;
    *(s16x8*)&Sb[base + (size_t)row * DMODEL + u8 * 8] =
        *(const s16x8*)&Ps[row * LDST + u8 * 8];
  }
}

// ---------------------------------------------------------------------------
// Output GEMM: out = Sb(4096x512 bf16) @ WO^T, fp32. 128x64 tile -> 256 blocks.
// ---------------------------------------------------------------------------
__global__ __launch_bounds__(256) void out_gemm_k(
    const unsigned short* __restrict__ A, const unsigned short* __restrict__ BT,
    float* __restrict__ out)
{
  __shared__ __align__(16) unsigned short As[128 * 64];
  __shared__ __align__(16) unsigned short Bs[64 * 64];
  const int n0 = blockIdx.x * 64;
  const int m0 = blockIdx.y * 128;
  const int tid = threadIdx.x;
  const int wave = tid >> 6, lane = tid & 63;
  const int wm = wave >> 1, wn = wave & 1;
  const int n = lane & 15, quad = lane >> 4;

  int srow[4], scol[4];
  #pragma unroll
  for (int r = 0; r < 4; ++r) {
    int idx = r * 256 + tid;
    srow[r] = idx >> 3;
    scol[r] = ((idx & 7) ^ (srow[r] & 7)) * 8;
  }

  f32x4 acc[4][2];
  #pragma unroll
  for (int mi = 0; mi < 4; ++mi)
    #pragma unroll
    for (int ni = 0; ni < 2; ++ni) acc[mi][ni] = (f32x4){0.f,0.f,0.f,0.f};

  for (int k0 = 0; k0 < 512; k0 += 64) {
    #pragma unroll
    for (int r = 0; r < 4; ++r) {
      int idx = r * 256 + tid;
      gld16(&As[idx * 8], &A[(size_t)(m0 + srow[r]) * DMODEL + k0 + scol[r]]);
    }
    #pragma unroll
    for (int r = 0; r < 2; ++r) {
      int idx = r * 256 + tid;
      gld16(&Bs[idx * 8], &BT[(size_t)(n0 + srow[r]) * DMODEL + k0 + scol[r]]);
    }
    __syncthreads();
    #pragma unroll
    for (int kk = 0; kk < 2; ++kk) {
      s16x8 af[4], bf[2];
      #pragma unroll
      for (int mi = 0; mi < 4; ++mi) {
        int R = wm*64 + mi*16 + n, cc = (kk*4 + quad) ^ (n & 7);
        af[mi] = *(const s16x8*)&As[R * 64 + cc * 8];
      }
      #pragma unroll
      for (int ni = 0; ni < 2; ++ni) {
        int R = wn*32 + ni*16 + n, cc = (kk*4 + quad) ^ (n & 7);
        bf[ni] = *(const s16x8*)&Bs[R * 64 + cc * 8];
      }
      #pragma unroll
      for (int mi = 0; mi < 4; ++mi)
        #pragma unroll
        for (int ni = 0; ni < 2; ++ni)
          acc[mi][ni] = __builtin_amdgcn_mfma_f32_16x16x32_bf16(
              af[mi], bf[ni], acc[mi][ni], 0, 0, 0);
    }
    __syncthreads();
  }

  #pragma unroll
  for (int mi = 0; mi < 4; ++mi)
    #pragma unroll
    for (int ni = 0; ni < 2; ++ni)
      #pragma unroll
      for (int r = 0; r < 4; ++r)
        out[(size_t)(m0 + wm*64 + mi*16 + quad*4 + r) * DMODEL +
            n0 + wn*32 + ni*16 + n] = acc[mi][ni][r];
}

// ---------------------------------------------------------------------------
extern "C" void kernel_launch(void* const* d_in, const int* in_sizes, int n_in,
                              void* d_out, int out_size, void* d_ws, size_t ws_size,
                              hipStream_t stream) {
  const float* x   = (const float*)d_in[0];
  const float* WQ  = (const float*)d_in[1];
  const float* WK  = (const float*)d_in[2];
  const float* WV  = (const float*)d_in[3];
  const float* WG  = (const float*)d_in[4];
  const float* WO  = (const float*)d_in[5];
  const float* gnw = (const float*)d_in[6];
  const float* gnb = (const float*)d_in[7];
  float* out = (float*)d_out;

  char* ws = (char*)d_ws;
  unsigned short* Xb = (unsigned short*)(ws);                 // 4 MB
  unsigned short* Qb = (unsigned short*)(ws + 4  * (1<<20));  // 4 MB
  unsigned short* Kb = (unsigned short*)(ws + 8  * (1<<20));  // 4 MB
  unsigned short* Vb = (unsigned short*)(ws + 12 * (1<<20));  // 4 MB
  unsigned short* G  = (unsigned short*)(ws + 16 * (1<<20));  // 4 MB (bf16)
  float* AT  = (float*)(ws + 24 * (1<<20));                   // 8 MB
  unsigned short* Sb = (unsigned short*)(ws + 32 * (1<<20));  // 4 MB
  unsigned short* WT = (unsigned short*)(ws + 40 * (1<<20));  // 2.5 MB
  (void)ws_size;

  // 1) fused cast-x + weight transpose/stacking
  prep_k<<<dim3(1024 + 320), 256, 0, stream>>>(x, Xb, WQ, WK, WV, WG, WO, WT);
  // 2) projections + fused per-chunk KV outer products
  proj_kv_k<<<dim3(16, M_ROWS / 128), 256, 0, stream>>>(
      Xb, WT, Qb, Kb, Vb, G, AT);
  // 3) fused parallel-scan + retention output + GroupNorm + gate + SiLU
  ret_o2_k<<<dim3(T_SEQ / 64, NH, 2), 256, 0, stream>>>(
      Qb, Kb, Vb, AT, G, gnw, gnb, Sb);
  // 4) output projection (fp32 out), 256 blocks
  out_gemm_k<<<dim3(8, M_ROWS / 128), 256, 0, stream>>>(
      Sb, WT + 2048 * DMODEL, out);
}

// Round 11
// 122.156 us; speedup vs baseline: 1.0321x; 1.0249x over previous
//
#include <hip/hip_runtime.h>
#include <hip/hip_bf16.h>
#include <math.h>

#define DMODEL 512
#define T_SEQ 2048
#define NH 8
#define DH 64
#define M_ROWS 4096
#define LDST 72   // padded LDS row stride (retention staging); 144 B = 16B-aligned
#define EPST 136  // epilogue repack stride (272 B = 16B-aligned, 2-way banks)

typedef short s16x8 __attribute__((ext_vector_type(8)));
typedef float f32x4 __attribute__((ext_vector_type(4)));

static __device__ __forceinline__ unsigned short f2bf(float f) {
  __hip_bfloat16 h = __float2bfloat16(f);
  return *(unsigned short*)&h;
}
static __device__ __forceinline__ float bf2f(unsigned short u) {
  union { unsigned int i; float f; } x; x.i = (unsigned int)u << 16; return x.f;
}
// async global->LDS 16B copy; LDS dest must be wave-uniform base + lane*16
static __device__ __forceinline__ void gld16(void* lds, const void* g) {
  __builtin_amdgcn_global_load_lds(
      (const __attribute__((address_space(1))) unsigned int*)g,
      (__attribute__((address_space(3))) unsigned int*)lds, 16, 0, 0);
}

// ---------------------------------------------------------------------------
// Fused prep: blocks 0..1023 cast x -> bf16; blocks 1024..1343 transpose+cast
// the 5 weight matrices into the stacked-row layout:
//   rows    0..511  : W_Q cols | rows 512..1535: [K_h|V_h] x 8 heads
//   rows 1536..2047 : W_G cols | rows 2048..2559: W_O cols
// ---------------------------------------------------------------------------
__global__ __launch_bounds__(256) void prep_k(
    const float* __restrict__ x, unsigned short* __restrict__ Xb,
    const float* __restrict__ W0, const float* __restrict__ W1,
    const float* __restrict__ W2, const float* __restrict__ W3,
    const float* __restrict__ W4, unsigned short* __restrict__ WT)
{
  __shared__ __align__(16) unsigned short buf[64 * LDST];
  const int bid = blockIdx.x, tid = threadIdx.x;
  if (bid < 1024) {
    const size_t i = ((size_t)bid * 256 + tid) * 8;
    float4 a = *(const float4*)&x[i];
    float4 b = *(const float4*)&x[i + 4];
    s16x8 o;
    o[0]=f2bf(a.x); o[1]=f2bf(a.y); o[2]=f2bf(a.z); o[3]=f2bf(a.w);
    o[4]=f2bf(b.x); o[5]=f2bf(b.y); o[6]=f2bf(b.z); o[7]=f2bf(b.w);
    *(s16x8*)&Xb[i] = o;
    return;
  }
  const int bid2 = bid - 1024;
  const int z = bid2 >> 6, rem = bid2 & 63;
  const int n0 = (rem & 7) * 64, k0 = (rem >> 3) * 64;
  const float* W = (z==0)?W0:(z==1)?W1:(z==2)?W2:(z==3)?W3:W4;
  int rowbase;
  if (z == 0)      rowbase = n0;
  else if (z == 1) rowbase = 512 + (n0 >> 6) * 128;        // K_h block
  else if (z == 2) rowbase = 512 + (n0 >> 6) * 128 + 64;   // V_h block
  else if (z == 3) rowbase = 1536 + n0;
  else             rowbase = 2048 + n0;
  #pragma unroll
  for (int r = 0; r < 4; ++r) {
    int idx = r * 256 + tid;
    int kr = idx >> 4, nc = idx & 15;
    float4 v = *(const float4*)&W[(size_t)(k0 + kr) * DMODEL + n0 + nc * 4];
    buf[(nc*4+0) * LDST + kr] = f2bf(v.x);
    buf[(nc*4+1) * LDST + kr] = f2bf(v.y);
    buf[(nc*4+2) * LDST + kr] = f2bf(v.z);
    buf[(nc*4+3) * LDST + kr] = f2bf(v.w);
  }
  __syncthreads();
  #pragma unroll
  for (int r = 0; r < 2; ++r) {
    int idx = r * 256 + tid;
    int nr = idx >> 3, c = idx & 7;
    *(s16x8*)&WT[((size_t)(rowbase + nr)) * DMODEL + k0 + c * 8] =
        *(const s16x8*)&buf[nr * LDST + c * 8];
  }
}

// ---------------------------------------------------------------------------
// Projection GEMM + fused KV outer product; b128 epilogue via LDS repack.
// ---------------------------------------------------------------------------
__global__ __launch_bounds__(256) void proj_kv_k(
    const unsigned short* __restrict__ A, const unsigned short* __restrict__ BT,
    unsigned short* __restrict__ Qb, unsigned short* __restrict__ Kb,
    unsigned short* __restrict__ Vb, unsigned short* __restrict__ Gb,
    float* __restrict__ AT)
{
  __shared__ __align__(16) unsigned short smem[128 * EPST]; // >= 2*128*64
  unsigned short* As = smem;
  unsigned short* Bs = smem + 128 * 64;
  const int ng0 = blockIdx.x * 128;
  const int m0 = blockIdx.y * 128;
  const int tid = threadIdx.x;
  const int wave = tid >> 6, lane = tid & 63;
  const int wm = wave >> 1, wn = wave & 1;
  const int n = lane & 15, quad = lane >> 4;

  int srow[4], scol[4];
  #pragma unroll
  for (int r = 0; r < 4; ++r) {
    int idx = r * 256 + tid;
    srow[r] = idx >> 3;
    scol[r] = ((idx & 7) ^ (srow[r] & 7)) * 8;
  }

  f32x4 acc[4][4];
  #pragma unroll
  for (int mi = 0; mi < 4; ++mi)
    #pragma unroll
    for (int ni = 0; ni < 4; ++ni) acc[mi][ni] = (f32x4){0.f,0.f,0.f,0.f};

  for (int k0 = 0; k0 < 512; k0 += 64) {
    #pragma unroll
    for (int r = 0; r < 4; ++r) {
      int idx = r * 256 + tid;
      gld16(&As[idx * 8], &A[(size_t)(m0 + srow[r]) * DMODEL + k0 + scol[r]]);
      gld16(&Bs[idx * 8], &BT[(size_t)(ng0 + srow[r]) * DMODEL + k0 + scol[r]]);
    }
    __syncthreads();
    #pragma unroll
    for (int kk = 0; kk < 2; ++kk) {
      s16x8 af[4], bf[4];
      #pragma unroll
      for (int mi = 0; mi < 4; ++mi) {
        int R = wm*64 + mi*16 + n, cc = (kk*4 + quad) ^ (n & 7);
        af[mi] = *(const s16x8*)&As[R * 64 + cc * 8];
      }
      #pragma unroll
      for (int ni = 0; ni < 4; ++ni) {
        int R = wn*64 + ni*16 + n, cc = (kk*4 + quad) ^ (n & 7);
        bf[ni] = *(const s16x8*)&Bs[R * 64 + cc * 8];
      }
      #pragma unroll
      for (int mi = 0; mi < 4; ++mi)
        #pragma unroll
        for (int ni = 0; ni < 4; ++ni)
          acc[mi][ni] = __builtin_amdgcn_mfma_f32_16x16x32_bf16(
              af[mi], bf[ni], acc[mi][ni], 0, 0, 0);
    }
    __syncthreads();
  }

  // ---- epilogue: repack acc via LDS (128 x EPST) -> b128 global stores ----
  unsigned short* Ep = smem;
  #pragma unroll
  for (int mi = 0; mi < 4; ++mi)
    #pragma unroll
    for (int ni = 0; ni < 4; ++ni)
      #pragma unroll
      for (int r = 0; r < 4; ++r)
        Ep[(wm*64 + mi*16 + quad*4 + r) * EPST + wn*64 + ni*16 + n] =
            f2bf(acc[mi][ni][r]);
  __syncthreads();

  const int bx = blockIdx.x;
  if (bx < 4 || bx >= 12) {
    unsigned short* Cz = (bx < 4) ? Qb : Gb;
    const int n0 = (bx < 4) ? ng0 : (ng0 - 1536);
    #pragma unroll
    for (int t = 0; t < 8; ++t) {
      int idx = t * 256 + tid;
      int row = idx >> 4, u = idx & 15;
      *(s16x8*)&Cz[(size_t)(m0 + row) * DMODEL + n0 + u * 8] =
          *(const s16x8*)&Ep[row * EPST + u * 8];
    }
    return;
  }

  // KV tile: cols 0..63 = K_h, 64..127 = V_h
  const int h = (ng0 - 512) >> 7;
  const float lg = log2f(1.0f - exp2f(-5.0f - (float)h));
  #pragma unroll
  for (int t = 0; t < 4; ++t) {
    int idx = t * 256 + tid;
    int row = idx >> 3, u = idx & 7;
    *(s16x8*)&Kb[(size_t)(m0 + row) * DMODEL + h*DH + u * 8] =
        *(const s16x8*)&Ep[row * EPST + u * 8];
    *(s16x8*)&Vb[(size_t)(m0 + row) * DMODEL + h*DH + u * 8] =
        *(const s16x8*)&Ep[row * EPST + 64 + u * 8];
  }

  // fused AT: per 64-row chunk, stage scaled K^T and V^T, 8 MFMAs, store
  unsigned short* Kt = smem;                 // [d1][m], LDST stride
  unsigned short* Vt = smem + 64 * LDST;
  #pragma unroll
  for (int cc2 = 0; cc2 < 2; ++cc2) {
    __syncthreads();   // orders Ep reads / prev chunk's MFMA before restage
    if (wm == cc2) {
      unsigned short* Tt = (wn == 0) ? Kt : Vt;
      #pragma unroll
      for (int mi = 0; mi < 4; ++mi)
        #pragma unroll
        for (int r = 0; r < 4; ++r) {
          int m = mi*16 + quad*4 + r;
          float sc = (wn == 0) ? exp2f((float)(64 - m) * lg) : 1.0f;
          #pragma unroll
          for (int ni = 0; ni < 4; ++ni)
            Tt[(ni*16 + n) * LDST + m] = f2bf(acc[mi][ni][r] * sc);
        }
    }
    __syncthreads();
    f32x4 at[4];
    #pragma unroll
    for (int j = 0; j < 4; ++j) at[j] = (f32x4){0.f,0.f,0.f,0.f};
    #pragma unroll
    for (int kk = 0; kk < 2; ++kk) {
      s16x8 a = *(const s16x8*)&Vt[(wave*16 + n) * LDST + kk*32 + quad*8];
      #pragma unroll
      for (int j = 0; j < 4; ++j) {
        s16x8 bf = *(const s16x8*)&Kt[(j*16 + n) * LDST + kk*32 + quad*8];
        at[j] = __builtin_amdgcn_mfma_f32_16x16x32_bf16(a, bf, at[j], 0, 0, 0);
      }
    }
    const int gr = m0 + cc2 * 64;
    const int bb = gr >> 11, cchunk = (gr & 2047) >> 6;
    float* Ab = AT + (((size_t)(bb * NH + h) * 32 + cchunk) << 12);
    #pragma unroll
    for (int j = 0; j < 4; ++j)
      #pragma unroll
      for (int r = 0; r < 4; ++r)
        Ab[(wave*16 + quad*4 + r) * 64 + j*16 + n] = at[j][r];
  }
}

// ---------------------------------------------------------------------------
// Fused scan + retention output + GroupNorm + gate + SiLU (unchanged, R10).
// ---------------------------------------------------------------------------
__global__ __launch_bounds__(256) void ret_o2_k(
    const unsigned short* __restrict__ Qb, const unsigned short* __restrict__ Kb,
    const unsigned short* __restrict__ Vb, const float* __restrict__ AT,
    const unsigned short* __restrict__ Gg, const float* __restrict__ gnw,
    const float* __restrict__ gnb, unsigned short* __restrict__ Sb)
{
  __shared__ __align__(16) unsigned short Qs[64 * 64];    // swizzled
  __shared__ __align__(16) unsigned short Ks[64 * 64];    // swizzled
  __shared__ __align__(16) unsigned short Vst[64 * LDST]; // [d2][m]
  __shared__ __align__(16) unsigned short Ss[64 * LDST];  // [d2][d1]
  __shared__ __align__(16) unsigned short Ps[64 * LDST];
  const int c = (int)gridDim.x - 1 - (int)blockIdx.x;     // heavy chunks first
  const int h = blockIdx.y, b = blockIdx.z;
  const int bh = b * NH + h;
  const int tid = threadIdx.x;
  const int wave = tid >> 6, lane = tid & 63;
  const int n = lane & 15, quad = lane >> 4;
  const size_t base = ((size_t)b * T_SEQ + (size_t)c * 64) * DMODEL + h * DH;
  const float lg = log2f(1.0f - exp2f(-5.0f - (float)h));
  const float lg64 = 64.0f * lg;

  // stage Q, K (async, swizzled) and V^T (VGPR transpose path)
  #pragma unroll
  for (int r = 0; r < 2; ++r) {
    int idx = r * 256 + tid;
    int row = idx >> 3, sc = ((idx & 7) ^ (row & 7)) * 8;
    gld16(&Qs[idx * 8], &Qb[base + (size_t)row * DMODEL + sc]);
    gld16(&Ks[idx * 8], &Kb[base + (size_t)row * DMODEL + sc]);
  }
  #pragma unroll
  for (int r = 0; r < 2; ++r) {
    int idx = r * 256 + tid;
    int m = idx & 63, ch = idx >> 6;
    s16x8 vv = *(const s16x8*)&Vb[base + (size_t)m * DMODEL + ch * 8];
    #pragma unroll
    for (int e = 0; e < 8; ++e)
      Vst[(ch * 8 + e) * LDST + m] = ((unsigned short*)&vv)[e];
  }

  // parallel weighted-sum scan: S_c = sum_{cp<c} g64^(c-1-cp) * A[cp]
  const float* Ac = AT + (((size_t)bh * 32) << 12) + (size_t)tid * 16;
  float4 S0 = {0,0,0,0}, S1 = S0, S2 = S0, S3 = S0;
  #pragma unroll 4
  for (int cp = 0; cp < c; ++cp) {
    const float* p = Ac + ((size_t)cp << 12);
    const float w = exp2f((float)(c - 1 - cp) * lg64);
    float4 a0 = *(const float4*)(p + 0);
    float4 a1 = *(const float4*)(p + 4);
    float4 a2 = *(const float4*)(p + 8);
    float4 a3 = *(const float4*)(p + 12);
    S0.x = fmaf(w, a0.x, S0.x); S0.y = fmaf(w, a0.y, S0.y);
    S0.z = fmaf(w, a0.z, S0.z); S0.w = fmaf(w, a0.w, S0.w);
    S1.x = fmaf(w, a1.x, S1.x); S1.y = fmaf(w, a1.y, S1.y);
    S1.z = fmaf(w, a1.z, S1.z); S1.w = fmaf(w, a1.w, S1.w);
    S2.x = fmaf(w, a2.x, S2.x); S2.y = fmaf(w, a2.y, S2.y);
    S2.z = fmaf(w, a2.z, S2.z); S2.w = fmaf(w, a2.w, S2.w);
    S3.x = fmaf(w, a3.x, S3.x); S3.y = fmaf(w, a3.y, S3.y);
    S3.z = fmaf(w, a3.z, S3.z); S3.w = fmaf(w, a3.w, S3.w);
  }
  {
    const int d2 = tid >> 2, d1b = (tid & 3) * 16;
    s16x8 lo, hi;
    lo[0]=f2bf(S0.x); lo[1]=f2bf(S0.y); lo[2]=f2bf(S0.z); lo[3]=f2bf(S0.w);
    lo[4]=f2bf(S1.x); lo[5]=f2bf(S1.y); lo[6]=f2bf(S1.z); lo[7]=f2bf(S1.w);
    hi[0]=f2bf(S2.x); hi[1]=f2bf(S2.y); hi[2]=f2bf(S2.z); hi[3]=f2bf(S2.w);
    hi[4]=f2bf(S3.x); hi[5]=f2bf(S3.y); hi[6]=f2bf(S3.z); hi[7]=f2bf(S3.w);
    *(s16x8*)&Ss[d2 * LDST + d1b] = lo;
    *(s16x8*)&Ss[d2 * LDST + d1b + 8] = hi;
  }
  __syncthreads();  // drains Q/K gld16 + Vst/Ss writes

  f32x4 s[4], u[4];
  #pragma unroll
  for (int j = 0; j < 4; ++j) {
    s[j] = (f32x4){0.f,0.f,0.f,0.f};
    u[j] = (f32x4){0.f,0.f,0.f,0.f};
  }
  const int RA = wave*16 + n;
  #pragma unroll
  for (int kk = 0; kk < 2; ++kk) {
    s16x8 a = *(const s16x8*)&Qs[RA * 64 + (((kk*4 + quad) ^ (RA & 7)) * 8)];
    #pragma unroll
    for (int j = 0; j < 4; ++j) {
      int RB = j*16 + n;
      s16x8 bk = *(const s16x8*)&Ks[RB * 64 + (((kk*4 + quad) ^ (RB & 7)) * 8)];
      s[j] = __builtin_amdgcn_mfma_f32_16x16x32_bf16(a, bk, s[j], 0, 0, 0);
      s16x8 bs = *(const s16x8*)&Ss[RB * LDST + kk*32 + quad*8];
      u[j] = __builtin_amdgcn_mfma_f32_16x16x32_bf16(a, bs, u[j], 0, 0, 0);
    }
  }

  float rowf[4], colf[4];
  #pragma unroll
  for (int r = 0; r < 4; ++r) rowf[r] = exp2f((float)(wave*16 + quad*4 + r) * lg);
  #pragma unroll
  for (int j = 0; j < 4; ++j) colf[j] = exp2f(-(float)(j*16 + n) * lg);

  #pragma unroll
  for (int j = 0; j < 4; ++j)
    #pragma unroll
    for (int r = 0; r < 4; ++r) {
      int i = wave*16 + quad*4 + r, mcol = j*16 + n;
      float v = (mcol <= i) ? s[j][r] * 0.125f * rowf[r] * colf[j] : 0.0f;
      Ps[i * LDST + mcol] = f2bf(v);
    }
  __syncthreads();  // all QK reads of Qs done; Ps ready

  // prefetch G tile into Qs (now dead) for the epilogue
  #pragma unroll
  for (int r = 0; r < 2; ++r) {
    int idx = r * 256 + tid;
    int row = idx >> 3, sc = ((idx & 7) ^ (row & 7)) * 8;
    gld16(&Qs[idx * 8], &Gg[base + (size_t)row * DMODEL + sc]);
  }

  f32x4 acc[4];
  #pragma unroll
  for (int j = 0; j < 4; ++j) acc[j] = (f32x4){0.f,0.f,0.f,0.f};
  #pragma unroll
  for (int kk = 0; kk < 2; ++kk) {
    s16x8 a = *(const s16x8*)&Ps[RA * LDST + kk*32 + quad*8];
    #pragma unroll
    for (int j = 0; j < 4; ++j) {
      s16x8 bf = *(const s16x8*)&Vst[(j*16 + n) * LDST + kk*32 + quad*8];
      acc[j] = __builtin_amdgcn_mfma_f32_16x16x32_bf16(a, bf, acc[j], 0, 0, 0);
    }
  }

  float ov[4][4];
  #pragma unroll
  for (int j = 0; j < 4; ++j)
    #pragma unroll
    for (int r = 0; r < 4; ++r)
      ov[j][r] = acc[j][r] + 0.125f * rowf[r] * u[j][r];

  float gw[4], gb[4];
  #pragma unroll
  for (int j = 0; j < 4; ++j) {
    gw[j] = gnw[h*DH + j*16 + n];
    gb[j] = gnb[h*DH + j*16 + n];
  }

  float normed[4][4];
  #pragma unroll
  for (int r = 0; r < 4; ++r) {
    float sum = ov[0][r] + ov[1][r] + ov[2][r] + ov[3][r];
    float sq  = ov[0][r]*ov[0][r] + ov[1][r]*ov[1][r]
              + ov[2][r]*ov[2][r] + ov[3][r]*ov[3][r];
    #pragma unroll
    for (int off = 8; off > 0; off >>= 1) {
      sum += __shfl_xor(sum, off, 64);
      sq  += __shfl_xor(sq,  off, 64);
    }
    const float mean = sum * (1.0f / 64.0f);
    float var = sq * (1.0f / 64.0f) - mean * mean;
    var = fmaxf(var, 0.0f);
    const float rstd = rsqrtf(var + 1e-5f);
    #pragma unroll
    for (int j = 0; j < 4; ++j)
      normed[j][r] = (ov[j][r] - mean) * rstd * gw[j] + gb[j];
  }

  __syncthreads();  // all PV reads of Ps done; G gld16 drained

  #pragma unroll
  for (int r = 0; r < 4; ++r) {
    const int i = wave*16 + quad*4 + r;
    #pragma unroll
    for (int j = 0; j < 4; ++j) {
      const int col = j*16 + n;
      const int gidx = i * 64 + (((col >> 3) ^ (i & 7)) * 8) + (col & 7);
      float uu = bf2f(Qs[gidx]) + normed[j][r];
      Ps[i * LDST + col] = f2bf(uu / (1.0f + expf(-uu)));
    }
  }
  __syncthreads();
  #pragma unroll
  for (int t = 0; t < 2; ++t) {
    int idx = t * 256 + tid;
    int row = idx >> 3, u8 = idx & 7;
    *(s16x8*)&Sb[base + (size_t)row * DMODEL + u8 * 8] =
        *(const s16x8*)&Ps[row * LDST + u8 * 8];
  }
}

// ---------------------------------------------------------------------------
// Output GEMM: out = Sb(4096x512 bf16) @ WO^T, fp32.
// 64x64 tiles -> grid 8x64 = 512 blocks = 2 blocks/CU (inter-block overlap
// hides the per-iteration vmcnt(0)+barrier drain; R10's 256-block version
// ran 1/CU with no overlap). 4 waves in 2x2, each 32x32 (acc 2x2).
// ---------------------------------------------------------------------------
__global__ __launch_bounds__(256) void out_gemm_k(
    const unsigned short* __restrict__ A, const unsigned short* __restrict__ BT,
    float* __restrict__ out)
{
  __shared__ __align__(16) unsigned short As[64 * 64];
  __shared__ __align__(16) unsigned short Bs[64 * 64];
  const int n0 = blockIdx.x * 64;
  const int m0 = blockIdx.y * 64;
  const int tid = threadIdx.x;
  const int wave = tid >> 6, lane = tid & 63;
  const int wm = wave >> 1, wn = wave & 1;
  const int n = lane & 15, quad = lane >> 4;

  int srow[2], scol[2];
  #pragma unroll
  for (int r = 0; r < 2; ++r) {
    int idx = r * 256 + tid;
    srow[r] = idx >> 3;
    scol[r] = ((idx & 7) ^ (srow[r] & 7)) * 8;
  }

  f32x4 acc[2][2];
  #pragma unroll
  for (int mi = 0; mi < 2; ++mi)
    #pragma unroll
    for (int ni = 0; ni < 2; ++ni) acc[mi][ni] = (f32x4){0.f,0.f,0.f,0.f};

  for (int k0 = 0; k0 < 512; k0 += 64) {
    #pragma unroll
    for (int r = 0; r < 2; ++r) {
      int idx = r * 256 + tid;
      gld16(&As[idx * 8], &A[(size_t)(m0 + srow[r]) * DMODEL + k0 + scol[r]]);
      gld16(&Bs[idx * 8], &BT[(size_t)(n0 + srow[r]) * DMODEL + k0 + scol[r]]);
    }
    __syncthreads();
    #pragma unroll
    for (int kk = 0; kk < 2; ++kk) {
      s16x8 af[2], bf[2];
      #pragma unroll
      for (int mi = 0; mi < 2; ++mi) {
        int R = wm*32 + mi*16 + n, cc = (kk*4 + quad) ^ (n & 7);
        af[mi] = *(const s16x8*)&As[R * 64 + cc * 8];
      }
      #pragma unroll
      for (int ni = 0; ni < 2; ++ni) {
        int R = wn*32 + ni*16 + n, cc = (kk*4 + quad) ^ (n & 7);
        bf[ni] = *(const s16x8*)&Bs[R * 64 + cc * 8];
      }
      #pragma unroll
      for (int mi = 0; mi < 2; ++mi)
        #pragma unroll
        for (int ni = 0; ni < 2; ++ni)
          acc[mi][ni] = __builtin_amdgcn_mfma_f32_16x16x32_bf16(
              af[mi], bf[ni], acc[mi][ni], 0, 0, 0);
    }
    __syncthreads();
  }

  #pragma unroll
  for (int mi = 0; mi < 2; ++mi)
    #pragma unroll
    for (int ni = 0; ni < 2; ++ni)
      #pragma unroll
      for (int r = 0; r < 4; ++r)
        out[(size_t)(m0 + wm*32 + mi*16 + quad*4 + r) * DMODEL +
            n0 + wn*32 + ni*16 + n] = acc[mi][ni][r];
}

// ---------------------------------------------------------------------------
extern "C" void kernel_launch(void* const* d_in, const int* in_sizes, int n_in,
                              void* d_out, int out_size, void* d_ws, size_t ws_size,
                              hipStream_t stream) {
  const float* x   = (const float*)d_in[0];
  const float* WQ  = (const float*)d_in[1];
  const float* WK  = (const float*)d_in[2];
  const float* WV  = (const float*)d_in[3];
  const float* WG  = (const float*)d_in[4];
  const float* WO  = (const float*)d_in[5];
  const float* gnw = (const float*)d_in[6];
  const float* gnb = (const float*)d_in[7];
  float* out = (float*)d_out;

  char* ws = (char*)d_ws;
  unsigned short* Xb = (unsigned short*)(ws);                 // 4 MB
  unsigned short* Qb = (unsigned short*)(ws + 4  * (1<<20));  // 4 MB
  unsigned short* Kb = (unsigned short*)(ws + 8  * (1<<20));  // 4 MB
  unsigned short* Vb = (unsigned short*)(ws + 12 * (1<<20));  // 4 MB
  unsigned short* G  = (unsigned short*)(ws + 16 * (1<<20));  // 4 MB (bf16)
  float* AT  = (float*)(ws + 24 * (1<<20));                   // 8 MB
  unsigned short* Sb = (unsigned short*)(ws + 32 * (1<<20));  // 4 MB
  unsigned short* WT = (unsigned short*)(ws + 40 * (1<<20));  // 2.5 MB
  (void)ws_size;

  // 1) fused cast-x + weight transpose/stacking
  prep_k<<<dim3(1024 + 320), 256, 0, stream>>>(x, Xb, WQ, WK, WV, WG, WO, WT);
  // 2) projections + fused per-chunk KV outer products
  proj_kv_k<<<dim3(16, M_ROWS / 128), 256, 0, stream>>>(
      Xb, WT, Qb, Kb, Vb, G, AT);
  // 3) fused parallel-scan + retention output + GroupNorm + gate + SiLU
  ret_o2_k<<<dim3(T_SEQ / 64, NH, 2), 256, 0, stream>>>(
      Qb, Kb, Vb, AT, G, gnw, gnb, Sb);
  // 4) output projection (fp32 out), 64x64 tiles, 512 blocks = 2/CU
  out_gemm_k<<<dim3(8, M_ROWS / 64), 256, 0, stream>>>(
      Sb, WT + 2048 * DMODEL, out);
}